// Round 3
// baseline (119.111 us; speedup 1.0000x reference)
//
#include <hip/hip_runtime.h>

// Problem constants (fixed by setup_inputs)
constexpr int T_TASKS = 256;
constexpr int NQ      = 300;
constexpr int NS      = 25;
constexpr int D       = 640;
constexpr int NWAY    = 5;
constexpr float LAMBDA_REG = 50.0f;

constexpr int SP4 = 161;        // float4 stride of one S row in LDS (644 floats)
constexpr int NT  = 1024;       // threads per block (16 waves)
constexpr int AC  = NS + NWAY;  // augmented columns = 30

// Pair-block table: 15 upper-triangle 5x5 blocks of the 25x25 Gram matrix
__device__ __constant__ int PA[15] = {0,0,0,0,0,1,1,1,1,2,2,2,3,3,4};
__device__ __constant__ int PB[15] = {0,1,2,3,4,1,2,3,4,2,3,4,3,4,4};

// ---------------------------------------------------------------------------
// Fused per-task kernel, one block per task (1 block/CU):
//   K = S S^T + lambda I  ->  X = 2 K^{-1} Y  ->  W = S^T X  ->
//   logits = scale * Q W
// Phase B processes all 5 query rows per 16-lane group in ONE pass so each
// W float4 from LDS is reused 5x (LDS issue drops ~5x vs round-per-row).
// ---------------------------------------------------------------------------
__global__ __launch_bounds__(NT) void fused_ridge_head_kernel(
    const float* __restrict__ query,    // (T, NQ, D)
    const float* __restrict__ support,  // (T, NS, D)
    const float* __restrict__ scale,    // (1,)
    const int*   __restrict__ labels,   // (T, NS)
    float*       __restrict__ out)      // (T, NQ, NWAY)
{
    __shared__ __align__(16) float4 sS4[NS * SP4];   // 64,400 B
    __shared__ __align__(16) float  sW[NWAY][D];     // 12,800 B
    __shared__ float aug[NS][32];                    //  3,200 B

    const int t   = blockIdx.x;
    const int tid = threadIdx.x;
    const float* Sg    = support + (size_t)t * NS * D;
    const float* Qbase = query   + (size_t)t * NQ * D;
    const float sc = scale[0];

    // ---- A1: stage S into LDS (coalesced float4) + RHS init ----------------
    for (int idx = tid; idx < NS * 160; idx += NT) {
        int s = idx / 160, f = idx % 160;
        sS4[s * SP4 + f] = reinterpret_cast<const float4*>(Sg)[idx];
    }
    if (tid >= 960) {                       // wave 15: RHS = 2 * onehot
        for (int idx = tid - 960; idx < NS * NWAY; idx += 64) {
            int s = idx / NWAY, w = idx % NWAY;
            aug[s][NS + w] = (labels[t * NS + s] == w) ? 2.0f : 0.0f;
        }
    }
    __syncthreads();

    // ---- A2: K = S S^T + lambda I, 5x5 register-blocked (waves 0..3) -------
    if (tid < 240) {
        const int grp = tid >> 4, l = tid & 15;
        const int ra = PA[grp] * 5, rb = PB[grp] * 5;
        float acc[25] = {};
        #pragma unroll
        for (int k = 0; k < 10; ++k) {
            const int f = l + 16 * k;
            float4 A[5], B[5];
            #pragma unroll
            for (int r = 0; r < 5; ++r) A[r] = sS4[(ra + r) * SP4 + f];
            #pragma unroll
            for (int r = 0; r < 5; ++r) B[r] = sS4[(rb + r) * SP4 + f];
            #pragma unroll
            for (int i = 0; i < 5; ++i)
                #pragma unroll
                for (int j = 0; j < 5; ++j)
                    acc[i * 5 + j] += A[i].x * B[j].x + A[i].y * B[j].y +
                                      A[i].z * B[j].z + A[i].w * B[j].w;
        }
        #pragma unroll
        for (int p = 0; p < 25; ++p) {
            #pragma unroll
            for (int off = 8; off >= 1; off >>= 1)
                acc[p] += __shfl_xor(acc[p], off);
        }
        if (l == 0) {
            #pragma unroll
            for (int p = 0; p < 25; ++p) {
                int i = ra + p / 5, j = rb + p % 5;
                float v = acc[p] + (i == j ? LAMBDA_REG : 0.0f);
                aug[i][j] = v;
                aug[j][i] = v;
            }
        }
    }
    __syncthreads();

    // Per-thread query-row offsets (float4 units); clamp tail rows to 299.
    const int g  = tid >> 4;      // 64 groups of 16 lanes; group g owns rows g+64j
    const int l4 = tid & 15;
    const float4* Qb4 = reinterpret_cast<const float4*>(Qbase);
    int off[5];
    #pragma unroll
    for (int j = 0; j < 5; ++j) {
        int q  = g + 64 * j;
        int qc = q < NQ ? q : NQ - 1;
        off[j] = qc * 160 + l4;
    }

    // ---- A3+A4 (wave 0 only): Gauss-Jordan in registers, then W = S^T X ----
    // Lane c owns column c of the 25x30 augmented system. No barriers inside.
    if (tid < 64) {
        const int  c      = tid;
        const bool active = (c < AC);
        float a[NS];
        #pragma unroll
        for (int r = 0; r < NS; ++r) a[r] = active ? aug[r][c] : 0.0f;
        #pragma unroll
        for (int k = 0; k < NS; ++k) {
            float piv = __shfl(a[k], k);    // aug[k][k]  (v_readlane)
            float inv = 1.0f / piv;
            a[k] *= inv;
            #pragma unroll
            for (int r = 0; r < NS; ++r) {
                if (r != k) {
                    float m = __shfl(a[r], k);
                    a[r] -= m * a[k];
                }
            }
        }
        // W[w][d] = sum_s S[s][d] * X[s][w]; lane c handles d = c + 64*ii.
        // X[s][w] lives in lane NS+w's a[s]; broadcast via readlane on the fly.
        const float* sSf = reinterpret_cast<const float*>(sS4);
        float accw[NWAY][10];
        #pragma unroll
        for (int w = 0; w < NWAY; ++w)
            #pragma unroll
            for (int ii = 0; ii < 10; ++ii) accw[w][ii] = 0.0f;
        #pragma unroll
        for (int s = 0; s < NS; ++s) {
            float X0 = __shfl(a[s], NS + 0);
            float X1 = __shfl(a[s], NS + 1);
            float X2 = __shfl(a[s], NS + 2);
            float X3 = __shfl(a[s], NS + 3);
            float X4 = __shfl(a[s], NS + 4);
            #pragma unroll
            for (int ii = 0; ii < 10; ++ii) {
                float sv = sSf[s * (SP4 * 4) + c + 64 * ii];
                accw[0][ii] += sv * X0;
                accw[1][ii] += sv * X1;
                accw[2][ii] += sv * X2;
                accw[3][ii] += sv * X3;
                accw[4][ii] += sv * X4;
            }
        }
        #pragma unroll
        for (int w = 0; w < NWAY; ++w)
            #pragma unroll
            for (int ii = 0; ii < 10; ++ii)
                sW[w][c + 64 * ii] = accw[w][ii];
    }

    // Prefetch i=0,1 for all 5 rows (waves 1..15 issue this while wave 0
    // is still in the solve; wave 0 issues it right after).
    float4 pf0[5], pf1[5];
    #pragma unroll
    for (int j = 0; j < 5; ++j) pf0[j] = Qb4[off[j]];
    #pragma unroll
    for (int j = 0; j < 5; ++j) pf1[j] = Qb4[off[j] + 16];

    __syncthreads();

    // ---- Phase B: logits = scale * Q W, 5 rows per group in one pass -------
    float acc[5][NWAY];
    #pragma unroll
    for (int j = 0; j < 5; ++j)
        #pragma unroll
        for (int w = 0; w < NWAY; ++w) acc[j][w] = 0.0f;

    #pragma unroll
    for (int i = 0; i < 10; ++i) {
        float4 qv[5];
        if (i == 0) {
            #pragma unroll
            for (int j = 0; j < 5; ++j) qv[j] = pf0[j];
        } else if (i == 1) {
            #pragma unroll
            for (int j = 0; j < 5; ++j) qv[j] = pf1[j];
        } else {
            #pragma unroll
            for (int j = 0; j < 5; ++j) qv[j] = Qb4[off[j] + i * 16];
        }
        const int dbase = i * 64 + 4 * l4;
        #pragma unroll
        for (int w = 0; w < NWAY; ++w) {
            const float4 wv = *reinterpret_cast<const float4*>(&sW[w][dbase]);
            #pragma unroll
            for (int j = 0; j < 5; ++j)
                acc[j][w] += qv[j].x * wv.x + qv[j].y * wv.y +
                             qv[j].z * wv.z + qv[j].w * wv.w;
        }
    }

    // Reduce across the 16-lane group, then lanes 0..4 store one row each.
    #pragma unroll
    for (int j = 0; j < 5; ++j) {
        #pragma unroll
        for (int w = 0; w < NWAY; ++w) {
            #pragma unroll
            for (int off2 = 8; off2 >= 1; off2 >>= 1)
                acc[j][w] += __shfl_xor(acc[j][w], off2);
        }
        const int q = g + 64 * j;
        float ov = acc[j][0];
        ov = (l4 == 1) ? acc[j][1] : ov;
        ov = (l4 == 2) ? acc[j][2] : ov;
        ov = (l4 == 3) ? acc[j][3] : ov;
        ov = (l4 == 4) ? acc[j][4] : ov;
        if (q < NQ && l4 < NWAY)
            out[((size_t)t * NQ + q) * NWAY + l4] = sc * ov;
    }
}

extern "C" void kernel_launch(void* const* d_in, const int* in_sizes, int n_in,
                              void* d_out, int out_size, void* d_ws, size_t ws_size,
                              hipStream_t stream) {
    const float* query   = (const float*)d_in[0];
    const float* support = (const float*)d_in[1];
    const float* scale   = (const float*)d_in[2];
    const int*   labels  = (const int*)d_in[3];
    float* out = (float*)d_out;

    fused_ridge_head_kernel<<<T_TASKS, NT, 0, stream>>>(query, support, scale, labels, out);
}

// Round 4
// 118.727 us; speedup vs baseline: 1.0032x; 1.0032x over previous
//
#include <hip/hip_runtime.h>

// Problem constants (fixed by setup_inputs)
constexpr int T_TASKS = 256;
constexpr int NQ      = 300;
constexpr int NS      = 25;
constexpr int D       = 640;
constexpr int NWAY    = 5;
constexpr float LAMBDA_REG = 50.0f;

constexpr int SP4 = 161;        // float4 stride of one S row in LDS (644 floats)
constexpr int NT  = 1024;       // threads per block (16 waves)
constexpr int AC  = NS + NWAY;  // augmented columns = 30

// Pair-block table: 15 upper-triangle 5x5 blocks of the 25x25 Gram matrix
__device__ __constant__ int PA[15] = {0,0,0,0,0,1,1,1,1,2,2,2,3,3,4};
__device__ __constant__ int PB[15] = {0,1,2,3,4,1,2,3,4,2,3,4,3,4,4};

// ---------------------------------------------------------------------------
// Fused per-task kernel, one block per task (1 block/CU):
//   K = S S^T + lambda I  ->  X = 2 K^{-1} Y  ->  W = S^T X  ->
//   logits = scale * Q W
// __launch_bounds__(1024, 4): 4 waves/SIMD = exactly one 16-wave block per CU
// -> 128 VGPR budget. R3's one-arg form let the compiler squeeze to 64 VGPR
// (2 blocks/CU) which spilled the ~100-reg live set to scratch (119 us).
// ---------------------------------------------------------------------------
__global__ __launch_bounds__(NT, 4) void fused_ridge_head_kernel(
    const float* __restrict__ query,    // (T, NQ, D)
    const float* __restrict__ support,  // (T, NS, D)
    const float* __restrict__ scale,    // (1,)
    const int*   __restrict__ labels,   // (T, NS)
    float*       __restrict__ out)      // (T, NQ, NWAY)
{
    __shared__ __align__(16) float4 sS4[NS * SP4];   // 64,400 B
    __shared__ __align__(16) float  sW[NWAY][D];     // 12,800 B
    __shared__ float aug[NS][32];                    //  3,200 B

    const int t   = blockIdx.x;
    const int tid = threadIdx.x;
    const float* Sg    = support + (size_t)t * NS * D;
    const float* Qbase = query   + (size_t)t * NQ * D;
    const float sc = scale[0];

    // ---- A1: stage S into LDS (coalesced float4) + RHS init ----------------
    for (int idx = tid; idx < NS * 160; idx += NT) {
        int s = idx / 160, f = idx % 160;
        sS4[s * SP4 + f] = reinterpret_cast<const float4*>(Sg)[idx];
    }
    if (tid >= 960) {                       // wave 15: RHS = 2 * onehot
        for (int idx = tid - 960; idx < NS * NWAY; idx += 64) {
            int s = idx / NWAY, w = idx % NWAY;
            aug[s][NS + w] = (labels[t * NS + s] == w) ? 2.0f : 0.0f;
        }
    }
    __syncthreads();

    // ---- A2: K = S S^T + lambda I, 5x5 register-blocked (waves 0..3) -------
    if (tid < 240) {
        const int grp = tid >> 4, l = tid & 15;
        const int ra = PA[grp] * 5, rb = PB[grp] * 5;
        float acc[25] = {};
        #pragma unroll
        for (int k = 0; k < 10; ++k) {
            const int f = l + 16 * k;
            float4 A[5], B[5];
            #pragma unroll
            for (int r = 0; r < 5; ++r) A[r] = sS4[(ra + r) * SP4 + f];
            #pragma unroll
            for (int r = 0; r < 5; ++r) B[r] = sS4[(rb + r) * SP4 + f];
            #pragma unroll
            for (int i = 0; i < 5; ++i)
                #pragma unroll
                for (int j = 0; j < 5; ++j)
                    acc[i * 5 + j] += A[i].x * B[j].x + A[i].y * B[j].y +
                                      A[i].z * B[j].z + A[i].w * B[j].w;
        }
        #pragma unroll
        for (int p = 0; p < 25; ++p) {
            #pragma unroll
            for (int off = 8; off >= 1; off >>= 1)
                acc[p] += __shfl_xor(acc[p], off);
        }
        if (l == 0) {
            #pragma unroll
            for (int p = 0; p < 25; ++p) {
                int i = ra + p / 5, j = rb + p % 5;
                float v = acc[p] + (i == j ? LAMBDA_REG : 0.0f);
                aug[i][j] = v;
                aug[j][i] = v;
            }
        }
    }
    __syncthreads();

    // Per-thread query-row offsets (float4 units); clamp tail rows to 299.
    const int g  = tid >> 4;      // 64 groups of 16 lanes; group g owns rows g+64j
    const int l4 = tid & 15;
    const float4* Qb4 = reinterpret_cast<const float4*>(Qbase);
    int off[5];
    #pragma unroll
    for (int j = 0; j < 5; ++j) {
        int q  = g + 64 * j;
        int qc = q < NQ ? q : NQ - 1;
        off[j] = qc * 160 + l4;
    }

    // ---- A3+A4 (wave 0 only): Gauss-Jordan in registers, then W = S^T X ----
    // Lane c owns column c of the 25x30 augmented system. No barriers inside.
    if (tid < 64) {
        const int  c      = tid;
        const bool active = (c < AC);
        float a[NS];
        #pragma unroll
        for (int r = 0; r < NS; ++r) a[r] = active ? aug[r][c] : 0.0f;
        #pragma unroll
        for (int k = 0; k < NS; ++k) {
            float piv = __shfl(a[k], k);    // aug[k][k]  (v_readlane)
            float inv = 1.0f / piv;
            a[k] *= inv;
            #pragma unroll
            for (int r = 0; r < NS; ++r) {
                if (r != k) {
                    float m = __shfl(a[r], k);
                    a[r] -= m * a[k];
                }
            }
        }
        // W[w][d] = sum_s S[s][d] * X[s][w]; lane c handles d = c + 64*ii.
        // X[s][w] lives in lane NS+w's a[s]; broadcast via readlane on the fly.
        const float* sSf = reinterpret_cast<const float*>(sS4);
        float accw[NWAY][10];
        #pragma unroll
        for (int w = 0; w < NWAY; ++w)
            #pragma unroll
            for (int ii = 0; ii < 10; ++ii) accw[w][ii] = 0.0f;
        #pragma unroll
        for (int s = 0; s < NS; ++s) {
            float X0 = __shfl(a[s], NS + 0);
            float X1 = __shfl(a[s], NS + 1);
            float X2 = __shfl(a[s], NS + 2);
            float X3 = __shfl(a[s], NS + 3);
            float X4 = __shfl(a[s], NS + 4);
            #pragma unroll
            for (int ii = 0; ii < 10; ++ii) {
                float sv = sSf[s * (SP4 * 4) + c + 64 * ii];
                accw[0][ii] += sv * X0;
                accw[1][ii] += sv * X1;
                accw[2][ii] += sv * X2;
                accw[3][ii] += sv * X3;
                accw[4][ii] += sv * X4;
            }
        }
        #pragma unroll
        for (int w = 0; w < NWAY; ++w)
            #pragma unroll
            for (int ii = 0; ii < 10; ++ii)
                sW[w][c + 64 * ii] = accw[w][ii];
    }

    // Prefetch i=0,1 for all 5 rows (waves 1..15 issue this while wave 0
    // is still in the solve; wave 0 issues it right after).
    float4 pf0[5], pf1[5];
    #pragma unroll
    for (int j = 0; j < 5; ++j) pf0[j] = Qb4[off[j]];
    #pragma unroll
    for (int j = 0; j < 5; ++j) pf1[j] = Qb4[off[j] + 16];

    __syncthreads();

    // ---- Phase B: logits = scale * Q W, 5 rows per group in one pass -------
    float acc[5][NWAY];
    #pragma unroll
    for (int j = 0; j < 5; ++j)
        #pragma unroll
        for (int w = 0; w < NWAY; ++w) acc[j][w] = 0.0f;

    #pragma unroll
    for (int i = 0; i < 10; ++i) {
        float4 qv[5];
        if (i == 0) {
            #pragma unroll
            for (int j = 0; j < 5; ++j) qv[j] = pf0[j];
        } else if (i == 1) {
            #pragma unroll
            for (int j = 0; j < 5; ++j) qv[j] = pf1[j];
        } else {
            #pragma unroll
            for (int j = 0; j < 5; ++j) qv[j] = Qb4[off[j] + i * 16];
        }
        const int dbase = i * 64 + 4 * l4;
        #pragma unroll
        for (int w = 0; w < NWAY; ++w) {
            const float4 wv = *reinterpret_cast<const float4*>(&sW[w][dbase]);
            #pragma unroll
            for (int j = 0; j < 5; ++j)
                acc[j][w] += qv[j].x * wv.x + qv[j].y * wv.y +
                             qv[j].z * wv.z + qv[j].w * wv.w;
        }
    }

    // Reduce across the 16-lane group, then lanes 0..4 store one row each.
    #pragma unroll
    for (int j = 0; j < 5; ++j) {
        #pragma unroll
        for (int w = 0; w < NWAY; ++w) {
            #pragma unroll
            for (int off2 = 8; off2 >= 1; off2 >>= 1)
                acc[j][w] += __shfl_xor(acc[j][w], off2);
        }
        const int q = g + 64 * j;
        float ov = acc[j][0];
        ov = (l4 == 1) ? acc[j][1] : ov;
        ov = (l4 == 2) ? acc[j][2] : ov;
        ov = (l4 == 3) ? acc[j][3] : ov;
        ov = (l4 == 4) ? acc[j][4] : ov;
        if (q < NQ && l4 < NWAY)
            out[((size_t)t * NQ + q) * NWAY + l4] = sc * ov;
    }
}

extern "C" void kernel_launch(void* const* d_in, const int* in_sizes, int n_in,
                              void* d_out, int out_size, void* d_ws, size_t ws_size,
                              hipStream_t stream) {
    const float* query   = (const float*)d_in[0];
    const float* support = (const float*)d_in[1];
    const float* scale   = (const float*)d_in[2];
    const int*   labels  = (const int*)d_in[3];
    float* out = (float*)d_out;

    fused_ridge_head_kernel<<<T_TASKS, NT, 0, stream>>>(query, support, scale, labels, out);
}